// Round 8
// baseline (191.109 us; speedup 1.0000x reference)
//
#include <hip/hip_runtime.h>
#include <math.h>

#define NB   16      // batch
#define NM   4096    // preds per image
#define NT   512     // targets per image
#define CAP  16      // max candidates per row (overflow -> exact fallback)
#define IOU_THR 0.1f
#define EPSG 1e-7f
#define NROWS (NB*NM)
#define T_AUC 512            // threads per auction block (== NT)
#define RPT   (NM / T_AUC)   // 8 rows per thread
#define CAPL  18432          // LDS CSR candidate slots per image
#define QCAP  6144           // LDS event-queue entries
#define POP_BUDGET 65536
#define SENTCLAIM 0xFFFFFFFFu

// ---------------------------------------------------------------------------
// Kernel 1: wave-per-row candidate build, targets staged in LDS per 64-row
// block (kills the 512 MB L2 re-read). Ballot compaction, ascending-j order,
// transposed (e-major) storage for coalesced consumption.
// ---------------------------------------------------------------------------
__global__ __launch_bounds__(256) void cand_kernel(
    const float4* __restrict__ pred, const float4* __restrict__ tgt,
    int* __restrict__ counts, float2* __restrict__ cands)
{
    __shared__ float4 t_lds[NT];
    const int rb = blockIdx.x * 64;          // 64 rows per block, same image
    const int b  = rb >> 12;                 // NM = 4096
    for (int i = threadIdx.x; i < NT; i += 256)
        t_lds[i] = tgt[b * NT + i];
    __syncthreads();

    const int wv = threadIdx.x >> 6, lane = threadIdx.x & 63;
    for (int rr = 0; rr < 16; ++rr) {
        const int row = rb + wv * 16 + rr;
        float4 p = pred[row];                // wave-uniform load
        float area_p = (p.z - p.x) * (p.w - p.y);
        int base = 0;
        #pragma unroll
        for (int pass = 0; pass < NT / 64; ++pass) {
            int j = (pass << 6) + lane;
            float4 t = t_lds[j];
            float area_t = (t.z - t.x) * (t.w - t.y);
            float w = fmaxf(fminf(p.z, t.z) - fmaxf(p.x, t.x), 0.f);
            float h = fmaxf(fminf(p.w, t.w) - fmaxf(p.y, t.y), 0.f);
            float inter = w * h;
            float uni   = (area_p + area_t) - inter;   // ref association
            float iou   = inter / uni;
            bool q = iou > IOU_THR;
            unsigned long long m = __ballot(q);
            if (q) {
                int off = base + __popcll(m & ((1ull << lane) - 1ull));
                if (off < CAP)
                    cands[(size_t)off * NROWS + row] = make_float2(iou, __int_as_float(j));
            }
            base += __popcll(m);
        }
        if (lane == 0) counts[row] = base;   // > CAP flags overflow
    }
}

// ---------------------------------------------------------------------------
// Kernel 2: event-driven auction to the unique fixed point (== serial greedy).
// claim[j] = min row ever proposing j (monotone). atomicMin's return value
// identifies the displaced holder -> pushed to an LDS work queue; any thread
// re-picks any row (state = claim + LDS CSR). Outer rounds: stateless sweep
// (certifies fixed point when it changes nothing) + barrier-free queue drain.
// ---------------------------------------------------------------------------
__global__ __launch_bounds__(T_AUC) void auction_kernel(
    const float4* __restrict__ pred, const float4* __restrict__ tgt,
    const int* __restrict__ counts, const float2* __restrict__ cands,
    float* __restrict__ per_img)
{
    __shared__ float4   t_lds[NT];                 // 8 KB
    __shared__ unsigned claim[NT];                 // 2 KB
    __shared__ float          ciou_s[CAPL + CAP];  // 72 KB
    __shared__ unsigned short cj_s[CAPL + CAP];    // 36 KB
    __shared__ unsigned short ofs_s[NM];           // 8 KB (0xFFFF -> global path)
    __shared__ unsigned char  cl_s[NM];            // 4 KB
    __shared__ unsigned qbuf[QCAP];                // 24 KB
    __shared__ int qhead, qtail, pending, flag;
    __shared__ int wsum[T_AUC / 64], wbase[T_AUC / 64];
    __shared__ int ovf_min, ovf_res;
    __shared__ float4 ovf_pred_s;
    __shared__ float rls[T_AUC / 64], rcs[T_AUC / 64], rvv[T_AUC / 64];
    __shared__ int   rjj[T_AUC / 64];

    const int b = blockIdx.x;
    const int t = threadIdx.x;
    const int gbase = b * NM;
    const int wv = t >> 6, lane = t & 63;
    volatile unsigned* vclaim = claim;
    volatile unsigned* vq     = qbuf;
    volatile int* vpend = &pending;
    volatile int* vqh   = &qhead;
    volatile int* vqt   = &qtail;

    t_lds[t] = tgt[b * NT + t];
    claim[t] = SENTCLAIM;

    // ---- per-row setup: counts, CSR offsets via block prefix sum ----
    int cl[RPT], ofs[RPT], ovfmj[RPT];
    unsigned ovfmask = 0u, matchedmask = 0u;
    int local = 0;
    #pragma unroll
    for (int k = 0; k < RPT; ++k) {
        int c = counts[gbase + t + k * T_AUC];
        if (c > CAP) ovfmask |= 1u << k;
        cl[k] = (c > 0 && c <= CAP) ? c : 0;
        local += cl[k];
        ovfmj[k] = -1;
    }
    int incl = local;
    #pragma unroll
    for (int d = 1; d < 64; d <<= 1) {
        int n = __shfl_up(incl, d);
        if (lane >= d) incl += n;
    }
    int excl = incl - local;
    if (lane == 63) wsum[wv] = incl;
    __syncthreads();
    if (t == 0) {
        int run = 0;
        for (int w = 0; w < T_AUC / 64; ++w) { wbase[w] = run; run += wsum[w]; }
    }
    __syncthreads();
    int base = wbase[wv] + excl;
    #pragma unroll
    for (int k = 0; k < RPT; ++k) {
        ofs[k] = (cl[k] > 0 && base + cl[k] <= CAPL) ? base : -1;
        base += cl[k];
    }
    #pragma unroll
    for (int k = 0; k < RPT; ++k) {
        int lrow = t + k * T_AUC;
        ofs_s[lrow] = (unsigned short)(ofs[k] >= 0 ? ofs[k] : 0xFFFF);
        cl_s[lrow]  = (unsigned char)cl[k];
        if (ofs[k] >= 0) {
            int grow = gbase + lrow;
            #pragma unroll
            for (int e = 0; e < CAP; ++e) {
                if (e < cl[k]) {
                    float2 c = cands[(size_t)e * NROWS + grow];
                    ciou_s[ofs[k] + e] = c.x;
                    cj_s[ofs[k] + e]   = (unsigned short)__float_as_int(c.y);
                }
            }
        }
    }
    __syncthreads();

    // ---- event primitives ----
    auto push_evt = [&](unsigned r2) {
        atomicAdd(&pending, 1);
        int s = atomicAdd(&qtail, 1);
        if (s < QCAP) qbuf[s] = r2;         // 32b store; stale reads are safe
        else atomicSub(&pending, 1);        // dropped: next sweep catches it
    };
    // re-pick row to a win or invalidity; push displaced holders; report changes
    auto process_row = [&](int row) -> bool {
        int o = ofs_s[row];
        int c = cl_s[row];
        bool changed = false;
        if (c == 0) return false;
        for (int it = 0; it <= CAP; ++it) {
            float bv = -1.f; int bj = -1;
            if (o != 0xFFFF) {
                #pragma unroll
                for (int e = 0; e < CAP; ++e) {          // padded, branch-free
                    float vi = ciou_s[o + e];
                    int j = cj_s[o + e] & (NT - 1);
                    unsigned cj = vclaim[j];
                    if (e < c && cj >= (unsigned)row && vi > bv) { bv = vi; bj = j; }
                }
            } else {                                     // CSR-capacity overflow row
                const float2* cp = cands + gbase + row;
                #pragma unroll
                for (int e = 0; e < CAP; ++e) {
                    float2 cc = make_float2(-1.f, 0.f);
                    if (e < c) cc = cp[(size_t)e * NROWS];
                    int j = __float_as_int(cc.y) & (NT - 1);
                    unsigned cj = vclaim[j];
                    if (e < c && cj >= (unsigned)row && cc.x > bv) { bv = cc.x; bj = j; }
                }
            }
            if (bj < 0) return changed;                  // invalid (permanent)
            unsigned old = atomicMin(&claim[bj], (unsigned)row);
            if (old >= (unsigned)row) {                  // won (old==row: re-confirm)
                if (old > (unsigned)row) {
                    changed = true;
                    if (old != SENTCLAIM) push_evt(old); // displaced exactly-the-holder
                }
                return changed;
            }
            // lost: bj permanently excluded (claim < row), retry
        }
        return changed;
    };
    auto drain_queue = [&]() {
        for (int it = 0; it < POP_BUDGET; ++it) {
            int h = *vqh, tl = *vqt;
            if (h < tl && h < QCAP) {
                if (atomicCAS(&qhead, h, h + 1) == h) {
                    unsigned r2 = vq[h] & (NM - 1);      // clamp: any row id is safe
                    process_row((int)r2);
                    atomicSub(&pending, 1);
                }
            } else if (*vpend == 0) break;
        }
    };

    // ---- outer rounds: sweep (fixed-point certificate) + event drain ----
    while (true) {
        __syncthreads();
        if (t == 0) { flag = 0; qhead = 0; qtail = 0; pending = 0; }
        __syncthreads();                                 // A
        bool ch = false;
        #pragma unroll
        for (int k = 0; k < RPT; ++k)
            ch |= process_row(t + k * T_AUC);
        drain_queue();
        if (ch) flag = 1;
        __syncthreads();                                 // B
        int f = flag;
        __syncthreads();                                 // C
        if (f) continue;

        // ---- overflow rows (count > CAP, ~never): exact serial fallback ----
        #pragma unroll
        for (int k = 0; k < RPT; ++k)                    // re-validate stolen matches
            if ((matchedmask >> k) & 1u)
                if (claim[ovfmj[k]] != (unsigned)(t + k * T_AUC))
                    matchedmask &= ~(1u << k);
        if (t == 0) ovf_min = 0x7FFFFFFF;
        __syncthreads();
        unsigned pend = ovfmask & ~matchedmask;
        #pragma unroll
        for (int k = 0; k < RPT; ++k)
            if ((pend >> k) & 1u) atomicMin(&ovf_min, t + k * T_AUC);
        __syncthreads();
        const int rowF = ovf_min;                        // uniform
        if (rowF == 0x7FFFFFFF) break;                   // converged, no ovf: done
        if (t == (rowF & (T_AUC - 1)))
            ovf_pred_s = pred[gbase + rowF];
        __syncthreads();
        {   // claim-aware argmax over all 512 targets (thread t = target t)
            float4 p4 = ovf_pred_s;
            float4 tt = t_lds[t];
            float area_p = (p4.z - p4.x) * (p4.w - p4.y);
            float area_t = (tt.z - tt.x) * (tt.w - tt.y);
            float w = fmaxf(fminf(p4.z, tt.z) - fmaxf(p4.x, tt.x), 0.f);
            float h = fmaxf(fminf(p4.w, tt.w) - fmaxf(p4.y, tt.y), 0.f);
            float inter = w * h;
            float iou = inter / ((area_p + area_t) - inter);
            bool freej = (claim[t] > (unsigned)rowF);
            float v = freej ? iou : -1.f;
            int bj = freej ? t : NT;
            #pragma unroll
            for (int off = 1; off < 64; off <<= 1) {
                float ov = __shfl_xor(v, off);
                int   oj = __shfl_xor(bj, off);
                if (ov > v || (ov == v && oj < bj)) { v = ov; bj = oj; }
            }
            if (lane == 0) { rvv[wv] = v; rjj[wv] = bj; }
        }
        __syncthreads();
        if (t == 0) {
            float v = rvv[0]; int bj = rjj[0];
            for (int w = 1; w < T_AUC / 64; ++w)
                if (rvv[w] > v || (rvv[w] == v && rjj[w] < bj)) { v = rvv[w]; bj = rjj[w]; }
            if (v > IOU_THR) { ovf_res = bj; claim[bj] = (unsigned)rowF; }  // steal
            else ovf_res = -1;
        }
        __syncthreads();
        if (t == (rowF & (T_AUC - 1))) {
            int k = rowF >> 9;                           // rowF / T_AUC
            if (ovf_res >= 0) { matchedmask |= 1u << k; ovfmj[k] = ovf_res; }
            else ovfmask &= ~(1u << k);                  // permanently invalid
        }
        // loop: displaced holder (if any) is re-picked by the next sweep
    }

    // ---- commit BY TARGET: claim[j]==r <=> r holds j (unique fixed point) ----
    __syncthreads();
    float ls = 0.f, cs = 0.f;
    {
        unsigned r = claim[t];
        if (r != SENTCLAIM) {
            float4 p4 = pred[gbase + (int)r];
            float4 tt = t_lds[t];
            float inter = fmaxf(fminf(p4.z, tt.z) - fmaxf(p4.x, tt.x), 0.f) *
                          fmaxf(fminf(p4.w, tt.w) - fmaxf(p4.y, tt.y), 0.f);
            float area_p = (p4.z - p4.x) * (p4.w - p4.y);
            float area_t = (tt.z - tt.x) * (tt.w - tt.y);
            float uni = area_p + area_t - inter;
            float iou = inter / (uni + EPSG);
            float enc = (fmaxf(p4.z, tt.z) - fminf(p4.x, tt.x)) *
                        (fmaxf(p4.w, tt.w) - fminf(p4.y, tt.y));
            float giou = iou - (enc - uni) / (enc + EPSG);
            ls = 1.f - giou;
            cs = 1.f;
        }
    }
    #pragma unroll
    for (int off = 32; off >= 1; off >>= 1) {
        ls += __shfl_xor(ls, off);
        cs += __shfl_xor(cs, off);
    }
    if (lane == 0) { rls[wv] = ls; rcs[wv] = cs; }
    __syncthreads();
    if (t == 0) {
        float L = 0.f, C = 0.f;
        for (int w = 0; w < T_AUC / 64; ++w) { L += rls[w]; C += rcs[w]; }
        per_img[b] = (C > 0.f) ? L / C : 0.f;
    }
}

// ---------------------------------------------------------------------------
// Kernel 3: mean over images -> scalar output. Deterministic (no atomics).
// ---------------------------------------------------------------------------
__global__ void reduce_kernel(const float* __restrict__ per_img,
                              float* __restrict__ out)
{
    if (threadIdx.x == 0 && blockIdx.x == 0) {
        float s = 0.f;
        for (int i = 0; i < NB; ++i) s += per_img[i];
        out[0] = s / (float)NB;
    }
}

extern "C" void kernel_launch(void* const* d_in, const int* in_sizes, int n_in,
                              void* d_out, int out_size, void* d_ws, size_t ws_size,
                              hipStream_t stream)
{
    const float4* pred = (const float4*)d_in[0];   // [16,4096,4] f32
    const float4* tgt  = (const float4*)d_in[1];   // [16,512,4]  f32

    char* ws = (char*)d_ws;
    // layout: counts [NROWS] i32 | cands [CAP*NROWS] float2 | per_img [NB] f32
    int*    counts  = (int*)ws;
    size_t  off1    = (size_t)NROWS * sizeof(int);                 // 256 KB
    float2* cands   = (float2*)(ws + off1);
    size_t  off2    = off1 + (size_t)CAP * NROWS * sizeof(float2); // +8 MB
    float*  per_img = (float*)(ws + off2);

    cand_kernel<<<NROWS / 64, 256, 0, stream>>>(pred, tgt, counts, cands);
    auction_kernel<<<NB, T_AUC, 0, stream>>>(pred, tgt, counts, cands, per_img);
    reduce_kernel<<<1, 64, 0, stream>>>(per_img, (float*)d_out);
}